// Round 8
// baseline (213.253 us; speedup 1.0000x reference)
//
#include <hip/hip_runtime.h>
#include <math.h>

// TokenRouter: LN(x) -> silu(x @ Wd^T) -> @ Wu^T -> top2 softmax
// H=2048, D=64, E=8, NTOK=16384, fp32 in/out.
//
// R16: R8 loop verbatim + halved `red` buffer -> 3 blocks/CU (TLP +50%).
//  Dead levers (all neutral): X prefetch depth (R10), X burst (R12), X
//  channel coalescing (R13), B volume (R14), B prefetch depth (R15).
//  Consistent with learn_hip m131-m140: hipcc re-schedules all source
//  pipeline variants to the same machine schedule; router sits at that
//  schedule's latency floor with all pipes slack (R13: VALU 16%, MFMA 6%,
//  HBM 12%). Only untested axis: occupancy (always 2 blocks/CU, LDS-bound
//  by red=73728B).
//  Fix: two-phase partial combine. Even waves (s=0,2,4,6) WRITE cell s/2;
//  barrier; odd waves ADD into the pair cell. IEEE add is commutative
//  bitwise, and pair sums are exactly the leaves of R8's reduction tree
//  ((p0+p1)+(p2+p3))+((p4+p5)+(p6+p7)) -> epilogue 4-way tree over cells
//  is BIT-IDENTICAL to R8 -> absmax 0.0 preserved.
//  LDS: red 4*64*36*4=36864 + stats/wu/BdCd ~4.6KB = ~41.5KB -> 3 blocks/
//  CU = 6 waves/SIMD. Inner loop = R8 byte-identical (proven 64 VGPR, no
//  spill) so the (512,4) 64-VGPR cap is safe AND 6 waves/SIMD fits VGPRs.
//  R9 lesson: #pragma unroll 2 only. R4: no runtime-indexed reg arrays.

#define H     2048
#define DBOT  64
#define NE    8
#define NTB   32              // tokens per block (one 32x32 A tile)
#define SPLIT 8               // K-split across waves
#define KSL   (H / SPLIT)     // 256 k per wave
#define NST   (KSL / 16)      // 16 MFMA k-steps per wave
#define RSTT  36              // combine row stride (32 tok + 4 pad)
#define WP_SHORTS (DBOT * H * 2)   // 262144 shorts = 512 KB

typedef short  bf16x8  __attribute__((ext_vector_type(8)));
typedef float  f32x4   __attribute__((ext_vector_type(4)));
typedef float  f32x16  __attribute__((ext_vector_type(16)));

__device__ __forceinline__ unsigned short bf16rne(float x) {
    unsigned u = __float_as_uint(x);
    return (unsigned short)((u + 0x7FFFu + ((u >> 16) & 1u)) >> 16);
}
__device__ __forceinline__ float bf16tof(unsigned short h) {
    return __uint_as_float(((unsigned)h) << 16);
}
// flat short index of the 8-short B-frag group (s,t,tj,hilo,kh,row n)
__device__ __forceinline__ int wp_idx(int s, int t, int tj, int hilo,
                                      int kh, int n) {
    return ((((((s * NST + t) * 2 + tj) * 2 + hilo) * 2 + kh) << 5) + n) << 3;
}

// ---------------- Kernel 1: preconvert W (R8 version) ----------------
__global__ __launch_bounds__(256) void prep_kernel(
    const float* __restrict__ Wd,     // [DBOT][H]
    const float* __restrict__ gamma,  // [H]
    const float* __restrict__ beta,   // [H]
    unsigned short* __restrict__ Wp,  // [WP_SHORTS]
    float* __restrict__ Bd,           // [DBOT]
    float* __restrict__ Cd)           // [DBOT]
{
    __shared__ float bred[4], cred[4];
    const int d   = blockIdx.x;
    const int tid = threadIdx.x;
    const int k0  = tid * 8;                   // 8 consecutive k, 8-aligned
    const int s   = k0 >> 8;
    const int t   = (k0 >> 4) & 15;
    const int kh  = (k0 >> 3) & 1;
    const int tj  = d >> 5;
    const int n   = d & 31;

    const float4 w0 = *(const float4*)&Wd[d * H + k0];
    const float4 w1 = *(const float4*)&Wd[d * H + k0 + 4];
    const float4 g0 = *(const float4*)&gamma[k0];
    const float4 g1 = *(const float4*)&gamma[k0 + 4];
    const float4 b0 = *(const float4*)&beta [k0];
    const float4 b1 = *(const float4*)&beta [k0 + 4];

    const float wg0 = w0.x * g0.x, wg1 = w0.y * g0.y;
    const float wg2 = w0.z * g0.z, wg3 = w0.w * g0.w;
    const float wg4 = w1.x * g1.x, wg5 = w1.y * g1.y;
    const float wg6 = w1.z * g1.z, wg7 = w1.w * g1.w;

    float bp = ((wg0 + wg1) + (wg2 + wg3)) + ((wg4 + wg5) + (wg6 + wg7));
    float cp = ((w0.x*b0.x + w0.y*b0.y) + (w0.z*b0.z + w0.w*b0.w))
             + ((w1.x*b1.x + w1.y*b1.y) + (w1.z*b1.z + w1.w*b1.w));

    ushort4 h0, h1, l0, l1;
    h0.x = bf16rne(wg0); h0.y = bf16rne(wg1);
    h0.z = bf16rne(wg2); h0.w = bf16rne(wg3);
    h1.x = bf16rne(wg4); h1.y = bf16rne(wg5);
    h1.z = bf16rne(wg6); h1.w = bf16rne(wg7);
    l0.x = bf16rne(wg0 - bf16tof(h0.x));
    l0.y = bf16rne(wg1 - bf16tof(h0.y));
    l0.z = bf16rne(wg2 - bf16tof(h0.z));
    l0.w = bf16rne(wg3 - bf16tof(h0.w));
    l1.x = bf16rne(wg4 - bf16tof(h1.x));
    l1.y = bf16rne(wg5 - bf16tof(h1.y));
    l1.z = bf16rne(wg6 - bf16tof(h1.z));
    l1.w = bf16rne(wg7 - bf16tof(h1.w));

    const int ih = wp_idx(s, t, tj, 0, kh, n);
    const int il = wp_idx(s, t, tj, 1, kh, n);
    *(ushort4*)&Wp[ih]     = h0;
    *(ushort4*)&Wp[ih + 4] = h1;
    *(ushort4*)&Wp[il]     = l0;
    *(ushort4*)&Wp[il + 4] = l1;

    // block-reduce bp/cp (4 waves)
    #pragma unroll
    for (int m = 1; m < 64; m <<= 1) {
        bp += __shfl_xor(bp, m);
        cp += __shfl_xor(cp, m);
    }
    if ((tid & 63) == 0) { bred[tid >> 6] = bp; cred[tid >> 6] = cp; }
    __syncthreads();
    if (tid == 0) {
        Bd[d] = (bred[0] + bred[1]) + (bred[2] + bred[3]);
        Cd[d] = (cred[0] + cred[1]) + (cred[2] + cred[3]);
    }
}

// ---------------- Kernel 2: main ----------------
__global__ __launch_bounds__(512, 4) void router_kernel(
    const float* __restrict__ X,            // [ntok][H]
    const unsigned short* __restrict__ Wp,  // preconverted W
    const float* __restrict__ Wu,           // [NE][DBOT]
    const float* __restrict__ Bd,
    const float* __restrict__ Cd,
    float* __restrict__ out,                // [ntok][NE]
    const int ntok)
{
    __shared__ float red[4 * DBOT * RSTT];   // 36864 B (pair cells)
    __shared__ float xsS[SPLIT][NTB], xqS[SPLIT][NTB];
    __shared__ float wuS[NE * DBOT];
    __shared__ float BdS[DBOT], CdS[DBOT];

    const int tid = threadIdx.x;
    const int s   = tid >> 6;        // wave = K-slice owner
    const int ln  = tid & 63;
    const int n   = ln & 31;         // A: token row / B: d row in tile
    const int kh  = ln >> 5;         // k-half within 16-k step
    const long tok0 = (long)blockIdx.x * NTB;

    if (tid < 128) ((float4*)wuS)[tid] = ((const float4*)Wu)[tid];
    if (tid < 64)  { BdS[tid] = Bd[tid]; CdS[tid] = Cd[tid]; }

    const bool xok = (tok0 + n) < ntok;
    const float* Xr = &X[(tok0 + n) * (long)H + s * KSL + kh * 8];
    const unsigned short* WpB = &Wp[wp_idx(s, 0, 0, 0, kh, n)];
    const int wstep = wp_idx(0, 1, 0, 0, 0, 0);          // 2048 shorts
    const int oB01  = wp_idx(0, 0, 0, 1, 0, 0);          // hilo stride 512
    const int oB10  = wp_idx(0, 0, 1, 0, 0, 0);          // tj stride 1024

    f32x16 acc0 = {}, acc1 = {};
    float xs = 0.f, xq = 0.f;

    const float4 z4 = make_float4(0.f, 0.f, 0.f, 0.f);
    float4 xa = xok ? *(const float4*)&Xr[0] : z4;
    float4 xb = xok ? *(const float4*)&Xr[4] : z4;
    bf16x8 B00 = *(const bf16x8*)&WpB[0];
    bf16x8 B01 = *(const bf16x8*)&WpB[oB01];
    bf16x8 B10 = *(const bf16x8*)&WpB[oB10];
    bf16x8 B11 = *(const bf16x8*)&WpB[oB10 + oB01];

    #pragma unroll 2
    for (int t = 0; t < NST; ++t) {
        // prefetch t+1
        float4 nxa = z4, nxb = z4;
        bf16x8 nB00 = {}, nB01 = {}, nB10 = {}, nB11 = {};
        if (t + 1 < NST) {
            if (xok) {
                nxa = *(const float4*)&Xr[(t + 1) * 16];
                nxb = *(const float4*)&Xr[(t + 1) * 16 + 4];
            }
            const unsigned short* wp = &WpB[(t + 1) * wstep];
            nB00 = *(const bf16x8*)&wp[0];
            nB01 = *(const bf16x8*)&wp[oB01];
            nB10 = *(const bf16x8*)&wp[oB10];
            nB11 = *(const bf16x8*)&wp[oB10 + oB01];
        }

        // stats + hi/lo convert of current X (8 values)
        xs += ((xa.x + xa.y) + (xa.z + xa.w)) + ((xb.x + xb.y) + (xb.z + xb.w));
        xq += ((xa.x*xa.x + xa.y*xa.y) + (xa.z*xa.z + xa.w*xa.w))
            + ((xb.x*xb.x + xb.y*xb.y) + (xb.z*xb.z + xb.w*xb.w));
        bf16x8 Ah, Al;
        Ah[0] = (short)bf16rne(xa.x); Ah[1] = (short)bf16rne(xa.y);
        Ah[2] = (short)bf16rne(xa.z); Ah[3] = (short)bf16rne(xa.w);
        Ah[4] = (short)bf16rne(xb.x); Ah[5] = (short)bf16rne(xb.y);
        Ah[6] = (short)bf16rne(xb.z); Ah[7] = (short)bf16rne(xb.w);
        Al[0] = (short)bf16rne(xa.x - bf16tof((unsigned short)Ah[0]));
        Al[1] = (short)bf16rne(xa.y - bf16tof((unsigned short)Ah[1]));
        Al[2] = (short)bf16rne(xa.z - bf16tof((unsigned short)Ah[2]));
        Al[3] = (short)bf16rne(xa.w - bf16tof((unsigned short)Ah[3]));
        Al[4] = (short)bf16rne(xb.x - bf16tof((unsigned short)Ah[4]));
        Al[5] = (short)bf16rne(xb.y - bf16tof((unsigned short)Ah[5]));
        Al[6] = (short)bf16rne(xb.z - bf16tof((unsigned short)Ah[6]));
        Al[7] = (short)bf16rne(xb.w - bf16tof((unsigned short)Ah[7]));

        acc0 = __builtin_amdgcn_mfma_f32_32x32x16_bf16(Ah, B00, acc0, 0, 0, 0);
        acc1 = __builtin_amdgcn_mfma_f32_32x32x16_bf16(Ah, B10, acc1, 0, 0, 0);
        acc0 = __builtin_amdgcn_mfma_f32_32x32x16_bf16(Ah, B01, acc0, 0, 0, 0);
        acc1 = __builtin_amdgcn_mfma_f32_32x32x16_bf16(Ah, B11, acc1, 0, 0, 0);
        acc0 = __builtin_amdgcn_mfma_f32_32x32x16_bf16(Al, B00, acc0, 0, 0, 0);
        acc1 = __builtin_amdgcn_mfma_f32_32x32x16_bf16(Al, B10, acc1, 0, 0, 0);

        xa = nxa; xb = nxb;
        B00 = nB00; B01 = nB01; B10 = nB10; B11 = nB11;
    }

    // ---- stats: fold kh pair, write wave partials
    xs += __shfl_xor(xs, 32);
    xq += __shfl_xor(xq, 32);
    if (ln < 32) { xsS[s][n] = xs; xqS[s][n] = xq; }

    // ---- two-phase partial combine into pair cells (s>>1):
    //  phase 1: even waves WRITE; phase 2: odd waves ADD.
    //  cell = p_even + p_odd == exact leaves of R8's reduction tree.
    {
        const int sh = s >> 1;
        float* rp0 = &red[(sh * DBOT + n) * RSTT + 4 * kh];        // tj=0: d=n
        float* rp1 = &red[(sh * DBOT + 32 + n) * RSTT + 4 * kh];   // tj=1
        const f32x4 a0 = {acc0[0],  acc0[1],  acc0[2],  acc0[3]};
        const f32x4 a1 = {acc0[4],  acc0[5],  acc0[6],  acc0[7]};
        const f32x4 a2 = {acc0[8],  acc0[9],  acc0[10], acc0[11]};
        const f32x4 a3 = {acc0[12], acc0[13], acc0[14], acc0[15]};
        const f32x4 b0 = {acc1[0],  acc1[1],  acc1[2],  acc1[3]};
        const f32x4 b1 = {acc1[4],  acc1[5],  acc1[6],  acc1[7]};
        const f32x4 b2 = {acc1[8],  acc1[9],  acc1[10], acc1[11]};
        const f32x4 b3 = {acc1[12], acc1[13], acc1[14], acc1[15]};

        if ((s & 1) == 0) {
            *(f32x4*)&rp0[0]  = a0;
            *(f32x4*)&rp0[8]  = a1;
            *(f32x4*)&rp0[16] = a2;
            *(f32x4*)&rp0[24] = a3;
            *(f32x4*)&rp1[0]  = b0;
            *(f32x4*)&rp1[8]  = b1;
            *(f32x4*)&rp1[16] = b2;
            *(f32x4*)&rp1[24] = b3;
        }
        __syncthreads();
        if (s & 1) {
            const f32x4 e0 = *(const f32x4*)&rp0[0];
            const f32x4 e1 = *(const f32x4*)&rp0[8];
            const f32x4 e2 = *(const f32x4*)&rp0[16];
            const f32x4 e3 = *(const f32x4*)&rp0[24];
            *(f32x4*)&rp0[0]  = e0 + a0;
            *(f32x4*)&rp0[8]  = e1 + a1;
            *(f32x4*)&rp0[16] = e2 + a2;
            *(f32x4*)&rp0[24] = e3 + a3;
            const f32x4 f0 = *(const f32x4*)&rp1[0];
            const f32x4 f1 = *(const f32x4*)&rp1[8];
            const f32x4 f2 = *(const f32x4*)&rp1[16];
            const f32x4 f3 = *(const f32x4*)&rp1[24];
            *(f32x4*)&rp1[0]  = f0 + b0;
            *(f32x4*)&rp1[8]  = f1 + b1;
            *(f32x4*)&rp1[16] = f2 + b2;
            *(f32x4*)&rp1[24] = f3 + b3;
        }
    }
    __syncthreads();

    // ---- epilogue: token = tid>>4; 16 threads/token; d = cq + 16*i
    {
        const int tok = tid >> 4;
        const int cq  = tid & 15;
        const float invH = 1.0f / (float)H;
        const float rsum = ((xsS[0][tok] + xsS[1][tok]) + (xsS[2][tok] + xsS[3][tok]))
                         + ((xsS[4][tok] + xsS[5][tok]) + (xsS[6][tok] + xsS[7][tok]));
        const float rsq  = ((xqS[0][tok] + xqS[1][tok]) + (xqS[2][tok] + xqS[3][tok]))
                         + ((xqS[4][tok] + xqS[5][tok]) + (xqS[6][tok] + xqS[7][tok]));
        const float mu   = rsum * invH;
        const float var  = rsq * invH - mu * mu;
        const float rstd = 1.0f / sqrtf(var + 1e-5f);

        float lg[NE];
        #pragma unroll
        for (int e = 0; e < NE; ++e) lg[e] = 0.f;
        #pragma unroll
        for (int i = 0; i < 4; ++i) {
            const int d = cq + 16 * i;
            // pair cells c0..c3; tree matches R8's 8-way tree bit-exactly
            const float A = ((red[(0*DBOT + d)*RSTT + tok] + red[(1*DBOT + d)*RSTT + tok])
                           + (red[(2*DBOT + d)*RSTT + tok] + red[(3*DBOT + d)*RSTT + tok]));
            const float t = rstd * (A - mu * BdS[d]) + CdS[d];
            const float z = t / (1.0f + expf(-t));
            #pragma unroll
            for (int e = 0; e < NE; ++e) lg[e] += z * wuS[e * DBOT + d];
        }
        #pragma unroll
        for (int e = 0; e < NE; ++e) {
            lg[e] += __shfl_xor(lg[e], 1);
            lg[e] += __shfl_xor(lg[e], 2);
            lg[e] += __shfl_xor(lg[e], 4);
            lg[e] += __shfl_xor(lg[e], 8);
        }

        if (cq == 0 && tok0 + tok < ntok) {
            // top-2; strict > keeps lowest index on ties (matches lax.top_k)
            float v1 = -INFINITY, v2 = -INFINITY;
            int i1 = -1, i2 = -1;
            #pragma unroll
            for (int e = 0; e < NE; ++e) {
                const float v = lg[e];
                if (v > v1)      { v2 = v1; i2 = i1; v1 = v; i1 = e; }
                else if (v > v2) { v2 = v;  i2 = e; }
            }
            const float e2  = expf(v2 - v1);
            const float inv = 1.0f / (1.0f + e2);
            float o[NE];
            #pragma unroll
            for (int e = 0; e < NE; ++e)
                o[e] = (e == i1) ? inv : ((e == i2) ? e2 * inv : 0.0f);
            float4* op = (float4*)&out[(tok0 + tok) * NE];
            op[0] = make_float4(o[0], o[1], o[2], o[3]);
            op[1] = make_float4(o[4], o[5], o[6], o[7]);
        }
    }
}

extern "C" void kernel_launch(void* const* d_in, const int* in_sizes, int n_in,
                              void* d_out, int out_size, void* d_ws, size_t ws_size,
                              hipStream_t stream) {
    const float* X     = (const float*)d_in[0];
    const float* Wd    = (const float*)d_in[1];
    const float* Wu    = (const float*)d_in[2];
    const float* gamma = (const float*)d_in[3];
    const float* beta  = (const float*)d_in[4];
    float* out = (float*)d_out;

    unsigned short* Wp = (unsigned short*)d_ws;                 // 512 KB
    float* Bd = (float*)((char*)d_ws + WP_SHORTS * sizeof(short));
    float* Cd = Bd + DBOT;

    const int ntok = in_sizes[0] / H;              // 16384
    const int nblk = (ntok + NTB - 1) / NTB;       // 512

    hipLaunchKernelGGL(prep_kernel, dim3(DBOT), dim3(256), 0, stream,
                       Wd, gamma, beta, Wp, Bd, Cd);
    hipLaunchKernelGGL(router_kernel, dim3(nblk), dim3(512), 0, stream,
                       X, Wp, Wu, Bd, Cd, out, ntok);
}